// Round 1
// baseline (65.815 us; speedup 1.0000x reference)
//
#include <hip/hip_runtime.h>
#include <hip/hip_bf16.h>
#include <math.h>

#define NCC 20
#define NQQ 27
#define BSZ 8192

__global__ __launch_bounds__(256) void matcher_kernel(
    const float* __restrict__ logits,    // (bs, NC*NQ)       flat: p*NQ + q
    const float* __restrict__ boxes,     // (bs, NC*NQ, 6)    flat: (p*NQ+q)*6 + d
    const float* __restrict__ tboxes,    // (bs, NC, 6)       flat: p*6 + d
    const int*   __restrict__ present,   // (bs, NC)          flat: p
    float* __restrict__ out_matches,     // (bs, NC, NQ) as float 0/1
    float* __restrict__ out_soft)        // (bs, NC, NQ)
{
    const int p = blockIdx.x * blockDim.x + threadIdx.x;   // (b,c) pair index
    if (p >= BSZ * NCC) return;

    // ---- target box (cx,cy,cz,w,h,d) -> xyzxyz ----
    const float* t = tboxes + (size_t)p * 6;
    float2 t01 = *reinterpret_cast<const float2*>(t + 0);
    float2 t23 = *reinterpret_cast<const float2*>(t + 2);
    float2 t45 = *reinterpret_cast<const float2*>(t + 4);
    const float tc0 = t01.x, tc1 = t01.y, tc2 = t23.x;
    const float tw  = t23.y, th  = t45.x, td  = t45.y;
    const float tl0 = tc0 - 0.5f * tw, tl1 = tc1 - 0.5f * th, tl2 = tc2 - 0.5f * td;
    const float th0 = tc0 + 0.5f * tw, th1 = tc1 + 0.5f * th, th2 = tc2 + 0.5f * td;
    const float vol_t = (th0 - tl0) * (th1 - tl1) * (th2 - tl2);

    float cg[NQQ];               // cost_giou per query (register array, const-indexed)
    float minC = INFINITY;
    int   minIdx = 0;
    float gmax = -INFINITY, gmin = INFINITY;

    const float* bq_base = boxes + (size_t)p * NQQ * 6;
    const float* lg_base = logits + (size_t)p * NQQ;

#pragma unroll
    for (int q = 0; q < NQQ; ++q) {
        // box loads: 8-byte aligned (648*p + 24*q)
        float2 b01 = *reinterpret_cast<const float2*>(bq_base + q * 6 + 0);
        float2 b23 = *reinterpret_cast<const float2*>(bq_base + q * 6 + 2);
        float2 b45 = *reinterpret_cast<const float2*>(bq_base + q * 6 + 4);
        const float bc0 = b01.x, bc1 = b01.y, bc2 = b23.x;
        const float bw  = b23.y, bh  = b45.x, bd  = b45.y;
        const float lg  = lg_base[q];

        // cost_class = -sigmoid(logit)
        const float cost_class = -1.0f / (1.0f + expf(-lg));

        // cost_bbox: L1 in cxcyczwhd space, UNclipped boxes
        const float cost_bbox =
            fabsf(bc0 - tc0) + fabsf(bc1 - tc1) + fabsf(bc2 - tc2) +
            fabsf(bw  - tw ) + fabsf(bh  - th ) + fabsf(bd  - td );

        // giou on clipped pred boxes
        const float cc0 = fmaxf(bc0, 0.0f), cc1 = fmaxf(bc1, 0.0f), cc2 = fmaxf(bc2, 0.0f);
        const float cw  = fmaxf(bw , 0.0f), ch  = fmaxf(bh , 0.0f), cd  = fmaxf(bd , 0.0f);
        const float pl0 = cc0 - 0.5f * cw, pl1 = cc1 - 0.5f * ch, pl2 = cc2 - 0.5f * cd;
        const float ph0 = cc0 + 0.5f * cw, ph1 = cc1 + 0.5f * ch, ph2 = cc2 + 0.5f * cd;
        const float vol_p = (ph0 - pl0) * (ph1 - pl1) * (ph2 - pl2);

        const float i0 = fmaxf(fminf(ph0, th0) - fmaxf(pl0, tl0), 0.0f);
        const float i1 = fmaxf(fminf(ph1, th1) - fmaxf(pl1, tl1), 0.0f);
        const float i2 = fmaxf(fminf(ph2, th2) - fmaxf(pl2, tl2), 0.0f);
        const float inter = i0 * i1 * i2;
        const float uni   = vol_p + vol_t - inter;
        const float iou   = inter / uni;

        const float h0 = fmaxf(fmaxf(ph0, th0) - fminf(pl0, tl0), 0.0f);
        const float h1 = fmaxf(fmaxf(ph1, th1) - fminf(pl1, tl1), 0.0f);
        const float h2 = fmaxf(fmaxf(ph2, th2) - fminf(pl2, tl2), 0.0f);
        const float hull = h0 * h1 * h2;

        const float giou = iou - (hull - uni) / hull;
        const float cost_giou = -giou;
        cg[q] = cost_giou;
        gmax = fmaxf(gmax, cost_giou);
        gmin = fminf(gmin, cost_giou);

        const float C = 5.0f * cost_bbox + 2.0f * cost_class + 2.0f * cost_giou;
        if (C < minC) { minC = C; minIdx = q; }
    }

    // ---- outputs ----
    const int  pres  = present[p];
    const float inv_den = 1.0f / (gmin - gmax);   // <= 0; NaN only if degenerate (matches ref)
    float* om = out_matches + (size_t)p * NQQ;
    float* os = out_soft    + (size_t)p * NQQ;

#pragma unroll
    for (int q = 0; q < NQQ; ++q) {
        const float m = (pres && q == minIdx) ? 1.0f : 0.0f;
        float soft = fmaxf((cg[q] - gmax) * inv_den, 0.0f);
        om[q] = m;
        os[q] = pres ? soft : -1.0f;
    }
}

extern "C" void kernel_launch(void* const* d_in, const int* in_sizes, int n_in,
                              void* d_out, int out_size, void* d_ws, size_t ws_size,
                              hipStream_t stream) {
    const float* logits  = (const float*)d_in[0];
    const float* boxes   = (const float*)d_in[1];
    const float* tboxes  = (const float*)d_in[2];
    const int*   presnt  = (const int*)d_in[3];
    // d_in[4] = num_top_queries (always 1 per setup_inputs)

    float* out = (float*)d_out;
    float* out_matches = out;
    float* out_soft    = out + (size_t)BSZ * NCC * NQQ;

    const int total = BSZ * NCC;
    dim3 block(256);
    dim3 grid((total + 255) / 256);
    matcher_kernel<<<grid, block, 0, stream>>>(logits, boxes, tboxes, presnt,
                                               out_matches, out_soft);
}

// Round 2
// 39.357 us; speedup vs baseline: 1.6723x; 1.6723x over previous
//
#include <hip/hip_runtime.h>
#include <hip/hip_bf16.h>
#include <math.h>

#define NCC 20
#define NQQ 27
#define BSZ 8192
#define NPAIR (BSZ * NCC)

// 32 lanes per (b,c) pair; lane q in [0,27) handles query q.
__global__ __launch_bounds__(256) void matcher_kernel(
    const float* __restrict__ logits,    // (bs, NC*NQ)
    const float* __restrict__ boxes,     // (bs, NC*NQ, 6)
    const float* __restrict__ tboxes,    // (bs, NC, 6)
    const int*   __restrict__ present,   // (bs, NC)
    float* __restrict__ out_matches,     // (bs, NC, NQ) as float 0/1
    float* __restrict__ out_soft)        // (bs, NC, NQ)
{
    const int tid   = blockIdx.x * blockDim.x + threadIdx.x;
    const int p     = tid >> 5;          // pair index
    const int q     = tid & 31;          // query index within pair
    if (p >= NPAIR) return;
    const bool valid = (q < NQQ);

    // ---- target box (broadcast load: same address across the 32-lane group) ----
    const float* t = tboxes + (size_t)p * 6;
    float2 t01 = *reinterpret_cast<const float2*>(t + 0);
    float2 t23 = *reinterpret_cast<const float2*>(t + 2);
    float2 t45 = *reinterpret_cast<const float2*>(t + 4);
    const float tc0 = t01.x, tc1 = t01.y, tc2 = t23.x;
    const float tw  = t23.y, th  = t45.x, td  = t45.y;
    const float tl0 = tc0 - 0.5f * tw, tl1 = tc1 - 0.5f * th, tl2 = tc2 - 0.5f * td;
    const float th0 = tc0 + 0.5f * tw, th1 = tc1 + 0.5f * th, th2 = tc2 + 0.5f * td;
    const float vol_t = (th0 - tl0) * (th1 - tl1) * (th2 - tl2);

    // ---- per-lane query load (coalesced: 24B/lane contiguous) ----
    float cost_giou = 0.0f;
    float C = INFINITY;
    if (valid) {
        const float* bq = boxes + (size_t)p * (NQQ * 6) + q * 6;
        float2 b01 = *reinterpret_cast<const float2*>(bq + 0);
        float2 b23 = *reinterpret_cast<const float2*>(bq + 2);
        float2 b45 = *reinterpret_cast<const float2*>(bq + 4);
        const float bc0 = b01.x, bc1 = b01.y, bc2 = b23.x;
        const float bw  = b23.y, bh  = b45.x, bd  = b45.y;
        const float lg  = logits[(size_t)p * NQQ + q];

        const float cost_class = -1.0f / (1.0f + expf(-lg));

        const float cost_bbox =
            fabsf(bc0 - tc0) + fabsf(bc1 - tc1) + fabsf(bc2 - tc2) +
            fabsf(bw  - tw ) + fabsf(bh  - th ) + fabsf(bd  - td );

        // giou on clipped pred boxes
        const float cc0 = fmaxf(bc0, 0.0f), cc1 = fmaxf(bc1, 0.0f), cc2 = fmaxf(bc2, 0.0f);
        const float cw  = fmaxf(bw , 0.0f), ch  = fmaxf(bh , 0.0f), cd  = fmaxf(bd , 0.0f);
        const float pl0 = cc0 - 0.5f * cw, pl1 = cc1 - 0.5f * ch, pl2 = cc2 - 0.5f * cd;
        const float ph0 = cc0 + 0.5f * cw, ph1 = cc1 + 0.5f * ch, ph2 = cc2 + 0.5f * cd;
        const float vol_p = (ph0 - pl0) * (ph1 - pl1) * (ph2 - pl2);

        const float i0 = fmaxf(fminf(ph0, th0) - fmaxf(pl0, tl0), 0.0f);
        const float i1 = fmaxf(fminf(ph1, th1) - fmaxf(pl1, tl1), 0.0f);
        const float i2 = fmaxf(fminf(ph2, th2) - fmaxf(pl2, tl2), 0.0f);
        const float inter = i0 * i1 * i2;
        const float uni   = vol_p + vol_t - inter;
        const float iou   = inter / uni;

        const float h0 = fmaxf(fmaxf(ph0, th0) - fminf(pl0, tl0), 0.0f);
        const float h1 = fmaxf(fmaxf(ph1, th1) - fminf(pl1, tl1), 0.0f);
        const float h2 = fmaxf(fmaxf(ph2, th2) - fminf(pl2, tl2), 0.0f);
        const float hull = h0 * h1 * h2;

        const float giou = iou - (hull - uni) / hull;
        cost_giou = -giou;
        C = 5.0f * cost_bbox + 2.0f * cost_class + 2.0f * cost_giou;
    }

    // ---- 32-lane group reductions: argmin(C) w/ low-index tie-break, max/min(cg) ----
    int   idx = q;
    float gx  = valid ? cost_giou : -INFINITY;
    float gn  = valid ? cost_giou :  INFINITY;
#pragma unroll
    for (int m = 16; m >= 1; m >>= 1) {
        const float C2 = __shfl_xor(C,   m, 32);
        const int   i2 = __shfl_xor(idx, m, 32);
        if (C2 < C || (C2 == C && i2 < idx)) { C = C2; idx = i2; }
        gx = fmaxf(gx, __shfl_xor(gx, m, 32));
        gn = fminf(gn, __shfl_xor(gn, m, 32));
    }

    // ---- outputs (coalesced 27-float runs per pair) ----
    if (valid) {
        const int pres = present[p];
        const float soft = fmaxf((cost_giou - gx) / (gn - gx), 0.0f);
        out_matches[(size_t)p * NQQ + q] = (pres && q == idx) ? 1.0f : 0.0f;
        out_soft   [(size_t)p * NQQ + q] = pres ? soft : -1.0f;
    }
}

extern "C" void kernel_launch(void* const* d_in, const int* in_sizes, int n_in,
                              void* d_out, int out_size, void* d_ws, size_t ws_size,
                              hipStream_t stream) {
    const float* logits  = (const float*)d_in[0];
    const float* boxes   = (const float*)d_in[1];
    const float* tboxes  = (const float*)d_in[2];
    const int*   presnt  = (const int*)d_in[3];

    float* out = (float*)d_out;
    float* out_matches = out;
    float* out_soft    = out + (size_t)NPAIR * NQQ;

    const int total_threads = NPAIR * 32;           // 32 lanes per pair
    dim3 block(256);
    dim3 grid((total_threads + 255) / 256);         // 20480 blocks
    matcher_kernel<<<grid, block, 0, stream>>>(logits, boxes, tboxes, presnt,
                                               out_matches, out_soft);
}

// Round 3
// 35.677 us; speedup vs baseline: 1.8448x; 1.1031x over previous
//
#include <hip/hip_runtime.h>
#include <hip/hip_bf16.h>
#include <math.h>

#define NCC 20
#define NQQ 27
#define BSZ 8192
#define NPAIR (BSZ * NCC)

struct Tgt {
    float tc0, tc1, tc2, tw, th, td;
    float tl0, tl1, tl2, th0, th1, th2, vol;
};

__device__ __forceinline__ Tgt make_tgt(float2 t01, float2 t23, float2 t45) {
    Tgt T;
    T.tc0 = t01.x; T.tc1 = t01.y; T.tc2 = t23.x;
    T.tw  = t23.y; T.th  = t45.x; T.td  = t45.y;
    T.tl0 = T.tc0 - 0.5f * T.tw; T.tl1 = T.tc1 - 0.5f * T.th; T.tl2 = T.tc2 - 0.5f * T.td;
    T.th0 = T.tc0 + 0.5f * T.tw; T.th1 = T.tc1 + 0.5f * T.th; T.th2 = T.tc2 + 0.5f * T.td;
    T.vol = (T.th0 - T.tl0) * (T.th1 - T.tl1) * (T.th2 - T.tl2);
    return T;
}

// returns C; writes cost_giou to *cg
__device__ __forceinline__ float pair_cost(float2 b01, float2 b23, float2 b45,
                                           float lg, const Tgt& T, float* cg) {
    const float bc0 = b01.x, bc1 = b01.y, bc2 = b23.x;
    const float bw  = b23.y, bh  = b45.x, bd  = b45.y;

    const float cost_class = -1.0f / (1.0f + __expf(-lg));

    const float cost_bbox =
        fabsf(bc0 - T.tc0) + fabsf(bc1 - T.tc1) + fabsf(bc2 - T.tc2) +
        fabsf(bw  - T.tw ) + fabsf(bh  - T.th ) + fabsf(bd  - T.td );

    const float cc0 = fmaxf(bc0, 0.0f), cc1 = fmaxf(bc1, 0.0f), cc2 = fmaxf(bc2, 0.0f);
    const float cw  = fmaxf(bw , 0.0f), ch  = fmaxf(bh , 0.0f), cd  = fmaxf(bd , 0.0f);
    const float pl0 = cc0 - 0.5f * cw, pl1 = cc1 - 0.5f * ch, pl2 = cc2 - 0.5f * cd;
    const float ph0 = cc0 + 0.5f * cw, ph1 = cc1 + 0.5f * ch, ph2 = cc2 + 0.5f * cd;
    const float vol_p = (ph0 - pl0) * (ph1 - pl1) * (ph2 - pl2);

    const float i0 = fmaxf(fminf(ph0, T.th0) - fmaxf(pl0, T.tl0), 0.0f);
    const float i1 = fmaxf(fminf(ph1, T.th1) - fmaxf(pl1, T.tl1), 0.0f);
    const float i2 = fmaxf(fminf(ph2, T.th2) - fmaxf(pl2, T.tl2), 0.0f);
    const float inter = i0 * i1 * i2;
    const float uni   = vol_p + T.vol - inter;
    const float iou   = inter / uni;

    const float h0 = fmaxf(fmaxf(ph0, T.th0) - fminf(pl0, T.tl0), 0.0f);
    const float h1 = fmaxf(fmaxf(ph1, T.th1) - fminf(pl1, T.tl1), 0.0f);
    const float h2 = fmaxf(fmaxf(ph2, T.th2) - fminf(pl2, T.tl2), 0.0f);
    const float hull = h0 * h1 * h2;

    const float giou = iou - (hull - uni) / hull;
    *cg = -giou;
    return 5.0f * cost_bbox + 2.0f * cost_class + 2.0f * (-giou);
}

// 32 lanes per group; each group handles TWO consecutive pairs.
__global__ __launch_bounds__(256, 5) void matcher_kernel(
    const float* __restrict__ logits,    // (bs, NC*NQ)
    const float* __restrict__ boxes,     // (bs, NC*NQ, 6)
    const float* __restrict__ tboxes,    // (bs, NC, 6)
    const int*   __restrict__ present,   // (bs, NC)
    float* __restrict__ out_matches,
    float* __restrict__ out_soft)
{
    const int tid = blockIdx.x * blockDim.x + threadIdx.x;
    const int g   = tid >> 5;
    const int q   = tid & 31;
    const int p0  = g * 2;            // grid sized exactly: p0+1 < NPAIR always
    const int p1  = p0 + 1;
    const bool valid = (q < NQQ);
    const int qc = valid ? q : (NQQ - 1);   // clamp so invalid lanes load in-bounds

    // ---- issue ALL loads up front (max memory-level parallelism) ----
    const float* bq0 = boxes + (size_t)p0 * (NQQ * 6) + qc * 6;
    const float* bq1 = boxes + (size_t)p1 * (NQQ * 6) + qc * 6;
    float2 a01 = *reinterpret_cast<const float2*>(bq0 + 0);
    float2 a23 = *reinterpret_cast<const float2*>(bq0 + 2);
    float2 a45 = *reinterpret_cast<const float2*>(bq0 + 4);
    float2 c01 = *reinterpret_cast<const float2*>(bq1 + 0);
    float2 c23 = *reinterpret_cast<const float2*>(bq1 + 2);
    float2 c45 = *reinterpret_cast<const float2*>(bq1 + 4);
    const float lg0 = logits[(size_t)p0 * NQQ + qc];
    const float lg1 = logits[(size_t)p1 * NQQ + qc];
    const float* t0 = tboxes + (size_t)p0 * 6;
    const float* t1 = tboxes + (size_t)p1 * 6;
    float2 t0a = *reinterpret_cast<const float2*>(t0 + 0);
    float2 t0b = *reinterpret_cast<const float2*>(t0 + 2);
    float2 t0c = *reinterpret_cast<const float2*>(t0 + 4);
    float2 t1a = *reinterpret_cast<const float2*>(t1 + 0);
    float2 t1b = *reinterpret_cast<const float2*>(t1 + 2);
    float2 t1c = *reinterpret_cast<const float2*>(t1 + 4);
    const int pres0 = present[p0];
    const int pres1 = present[p1];

    const Tgt T0 = make_tgt(t0a, t0b, t0c);
    const Tgt T1 = make_tgt(t1a, t1b, t1c);

    float cg0, cg1;
    float C0 = pair_cost(a01, a23, a45, lg0, T0, &cg0);
    float C1 = pair_cost(c01, c23, c45, lg1, T1, &cg1);
    if (!valid) { C0 = INFINITY; C1 = INFINITY; }

    // ---- group reductions ----
    float m0 = C0, m1 = C1;
    float gx0 = valid ? cg0 : -INFINITY, gn0 = valid ? cg0 : INFINITY;
    float gx1 = valid ? cg1 : -INFINITY, gn1 = valid ? cg1 : INFINITY;
#pragma unroll
    for (int s = 16; s >= 1; s >>= 1) {
        m0  = fminf(m0,  __shfl_xor(m0,  s, 32));
        m1  = fminf(m1,  __shfl_xor(m1,  s, 32));
        gx0 = fmaxf(gx0, __shfl_xor(gx0, s, 32));
        gn0 = fminf(gn0, __shfl_xor(gn0, s, 32));
        gx1 = fmaxf(gx1, __shfl_xor(gx1, s, 32));
        gn1 = fminf(gn1, __shfl_xor(gn1, s, 32));
    }
    // argmin via ballot: lowest set bit = lowest q (tie-break == stable top_k)
    const unsigned long long b0 = __ballot(C0 == m0);
    const unsigned long long b1 = __ballot(C1 == m1);
    const int shift = (threadIdx.x & 32);             // which wave half this group is
    const unsigned int g0 = (unsigned int)(b0 >> shift);
    const unsigned int g1 = (unsigned int)(b1 >> shift);
    const int idx0 = __ffs(g0) - 1;
    const int idx1 = __ffs(g1) - 1;

    // ---- outputs ----
    if (valid) {
        const float s0 = fmaxf((cg0 - gx0) / (gn0 - gx0), 0.0f);
        const float s1 = fmaxf((cg1 - gx1) / (gn1 - gx1), 0.0f);
        out_matches[(size_t)p0 * NQQ + q] = (pres0 && q == idx0) ? 1.0f : 0.0f;
        out_matches[(size_t)p1 * NQQ + q] = (pres1 && q == idx1) ? 1.0f : 0.0f;
        out_soft   [(size_t)p0 * NQQ + q] = pres0 ? s0 : -1.0f;
        out_soft   [(size_t)p1 * NQQ + q] = pres1 ? s1 : -1.0f;
    }
}

extern "C" void kernel_launch(void* const* d_in, const int* in_sizes, int n_in,
                              void* d_out, int out_size, void* d_ws, size_t ws_size,
                              hipStream_t stream) {
    const float* logits  = (const float*)d_in[0];
    const float* boxes   = (const float*)d_in[1];
    const float* tboxes  = (const float*)d_in[2];
    const int*   presnt  = (const int*)d_in[3];

    float* out = (float*)d_out;
    float* out_matches = out;
    float* out_soft    = out + (size_t)NPAIR * NQQ;

    // NPAIR/2 groups * 32 lanes = 2,621,440 threads = exactly 10240 blocks of 256
    const int total_threads = (NPAIR / 2) * 32;
    dim3 block(256);
    dim3 grid(total_threads / 256);
    matcher_kernel<<<grid, block, 0, stream>>>(logits, boxes, tboxes, presnt,
                                               out_matches, out_soft);
}